// Round 14
// baseline (180.022 us; speedup 1.0000x reference)
//
#include <hip/hip_runtime.h>
#include <hip/hip_bf16.h>
#include <math.h>

// Problem sizes (fixed by reference): B=256, M=64, N=32, D=128, T=64, L=128
#define B_ 256
#define M_ 64
#define N_ 32
#define D_ 128
#define T_ 64
#define L_ 128

typedef __attribute__((ext_vector_type(8))) short short8;   // 8 bf16 = 4 VGPRs (MFMA A/B frag)
typedef __attribute__((ext_vector_type(4))) float floatx4;  // MFMA C/D frag

__device__ __forceinline__ unsigned short f2bf(float f) {
  unsigned int u = __float_as_uint(f);
  unsigned int r = (u + 0x7fffu + ((u >> 16) & 1u)) >> 16;  // RNE
  return (unsigned short)r;
}
__device__ __forceinline__ float bf2f(unsigned short s) {
  return __uint_as_float(((unsigned int)s) << 16);
}
__device__ __forceinline__ float frcp(float x) { return __builtin_amdgcn_rcpf(x); }

// ---------------------------------------------------------------------------
// K0: prep. blocks < 1024: x -> bf16 PI-PERMUTED xb2[m][b][pi(d)],
// pi(16i+j) = 8j+i (matches the order k_wpriors' entmax writes weights, so
// GEMM dot products are unchanged). block 1024: leaves norm. 1025: thrT.
// ---------------------------------------------------------------------------
__global__ __launch_bounds__(256) void k_prep(const float* __restrict__ x,
                                              const float* __restrict__ leaves,
                                              unsigned short* __restrict__ xb2,
                                              unsigned short* __restrict__ lhn,
                                              const float* __restrict__ thr,
                                              float* __restrict__ thrT) {
  const int tid = threadIdx.x;
  const int bx = blockIdx.x;
  if (bx < 1024) {
    int idx = bx * 256 + tid;          // (m, b, j)
    int j = idx & 15, b = (idx >> 4) & 255, m = idx >> 12;
    const float* xs = x + ((size_t)b * M_ + m) * D_ + j;   // d = 16i + j
    unsigned short pv[8];
#pragma unroll
    for (int i = 0; i < 8; ++i) pv[i] = f2bf(xs[i * 16]);
    unsigned short* dst = xb2 + ((size_t)m * B_ + b) * D_ + j * 8;  // pi pos 8j+i
    uint4 w;
    w.x = pv[0] | ((unsigned)pv[1] << 16);
    w.y = pv[2] | ((unsigned)pv[3] << 16);
    w.z = pv[4] | ((unsigned)pv[5] << 16);
    w.w = pv[6] | ((unsigned)pv[7] << 16);
    *(uint4*)dst = w;
  } else if (bx == 1024) {
    if (tid < L_) {
      const float* r = leaves + tid * T_;
      float ss = 0.f;
      for (int i = 0; i < T_; ++i) ss = fmaf(r[i], r[i], ss);
      float inv = frcp(fmaxf(sqrtf(ss), 1e-12f));
      unsigned short* o = lhn + tid * T_;
      for (int i = 0; i < T_; ++i) o[i] = f2bf(r[i] * inv);
    }
  } else {  // thrT[n][m] = thr[m][n]
#pragma unroll
    for (int k = 0; k < 8; ++k) {
      int idx = k * 256 + tid;
      int nn = idx >> 6, mm = idx & 63;
      thrT[idx] = thr[mm * N_ + nn];
    }
  }
}

// ---------------------------------------------------------------------------
// K1 (R14): fused entmax + priors GEMM, NO rw staging. Block = (m,n):
//  1. entmax reads rw DIRECTLY from global, float4 along T (64B-line
//     granularity): thread (g=tid>>4, j=tid&15) owns t=4g..4g+3 x d={16i+j}.
//     Reductions over d: regs (i) + shfl_xor(1,2,4,8) within j-groups.
//     Weights -> Bs[t][pi(d)=8j+i]: ONE ds_write_b128 per t.
//     [R13's rwT staging had structural 4-way LDS conflicts (3.67M cycles) +
//      32KB LDS + an extra barrier — all gone.]
//  2. GEMM (A=W from Bs, B=x from xb2, both pi-ordered) -> C[t][b];
//     Ct transpose -> 128B-contiguous stores to priors[n][b][m][t].
// LDS: Bs 17.4KB + Ct 18KB = 35.4KB -> 4 blocks/CU.
// ---------------------------------------------------------------------------
#define BS_STRIDE 136
__global__ __launch_bounds__(256, 4) void k_wpriors(const unsigned short* __restrict__ xb2,
                                                    const float* __restrict__ rw,
                                                    unsigned short* __restrict__ priors) {
  const int m = blockIdx.x, n = blockIdx.y;
  const int tid = threadIdx.x;
  const int wid = tid >> 6, lane = tid & 63;
  const int row16 = lane & 15, quad = lane >> 4;

  __shared__ __align__(16) unsigned short Bs[64 * BS_STRIDE];  // W [t][pi_k] bf16
  __shared__ __align__(16) unsigned short Ct[128 * 72];        // [b_local][t]

  // ---- 1. entmax (direct-global) ----
  {
    const int g = tid >> 4, j = tid & 15;
    const float* base = rw + (size_t)(m * N_ + n) * (D_ * T_) + g * 4;
    floatx4 xv[8];
#pragma unroll
    for (int i = 0; i < 8; ++i)
      xv[i] = *(const floatx4*)(base + (size_t)(i * 16 + j) * T_);

    floatx4 mx = xv[0];
#pragma unroll
    for (int i = 1; i < 8; ++i)
#pragma unroll
      for (int c = 0; c < 4; ++c) mx[c] = fmaxf(mx[c], xv[i][c]);
#pragma unroll
    for (int off = 1; off <= 8; off <<= 1)
#pragma unroll
      for (int c = 0; c < 4; ++c) mx[c] = fmaxf(mx[c], __shfl_xor(mx[c], off));
#pragma unroll
    for (int i = 0; i < 8; ++i)
#pragma unroll
      for (int c = 0; c < 4; ++c) xv[i][c] = (xv[i][c] - mx[c]) * 0.5f;

    floatx4 lo = (floatx4){-1.f, -1.f, -1.f, -1.f};
    floatx4 hi = (floatx4){0.f, 0.f, 0.f, 0.f};
    for (int it = 0; it < 10; ++it) {
      floatx4 tau, f = (floatx4){0.f, 0.f, 0.f, 0.f};
#pragma unroll
      for (int c = 0; c < 4; ++c) tau[c] = 0.5f * (lo[c] + hi[c]);
#pragma unroll
      for (int i = 0; i < 8; ++i)
#pragma unroll
        for (int c = 0; c < 4; ++c) {
          float u = fmaxf(xv[i][c] - tau[c], 0.0f);
          f[c] = fmaf(u, u, f[c]);
        }
#pragma unroll
      for (int off = 1; off <= 8; off <<= 1)
#pragma unroll
        for (int c = 0; c < 4; ++c) f[c] += __shfl_xor(f[c], off);
#pragma unroll
      for (int c = 0; c < 4; ++c) {
        bool ge = f[c] >= 1.0f;
        lo[c] = ge ? tau[c] : lo[c];
        hi[c] = ge ? hi[c] : tau[c];
      }
    }
    floatx4 tau0, cnt = (floatx4){0,0,0,0}, s1 = (floatx4){0,0,0,0}, s2 = (floatx4){0,0,0,0};
#pragma unroll
    for (int c = 0; c < 4; ++c) tau0[c] = 0.5f * (lo[c] + hi[c]);
#pragma unroll
    for (int i = 0; i < 8; ++i)
#pragma unroll
      for (int c = 0; c < 4; ++c) {
        bool in = xv[i][c] > tau0[c];
        float q = in ? xv[i][c] : 0.0f;
        cnt[c] += in ? 1.0f : 0.0f;
        s1[c] += q;
        s2[c] = fmaf(q, q, s2[c]);
      }
#pragma unroll
    for (int off = 1; off <= 8; off <<= 1)
#pragma unroll
      for (int c = 0; c < 4; ++c) {
        cnt[c] += __shfl_xor(cnt[c], off);
        s1[c] += __shfl_xor(s1[c], off);
        s2[c] += __shfl_xor(s2[c], off);
      }
    floatx4 tau;
#pragma unroll
    for (int c = 0; c < 4; ++c) {
      float rc = frcp(cnt[c]);
      float mean = s1[c] * rc;
      float ss = s2[c] - mean * s1[c];
      float delta = (1.0f - ss) * rc;
      tau[c] = mean - sqrtf(fmaxf(delta, 0.0f));
    }

    // weights -> Bs[t = 4g+c][pi = 8j + i]: one b128 write per t
#pragma unroll
    for (int c = 0; c < 4; ++c) {
      unsigned short pv[8];
#pragma unroll
      for (int i = 0; i < 8; ++i) {
        float u = fmaxf(xv[i][c] - tau[c], 0.0f);
        pv[i] = f2bf(u * u);
      }
      uint4 w;
      w.x = pv[0] | ((unsigned)pv[1] << 16);
      w.y = pv[2] | ((unsigned)pv[3] << 16);
      w.z = pv[4] | ((unsigned)pv[5] << 16);
      w.w = pv[6] | ((unsigned)pv[7] << 16);
      *(uint4*)&Bs[(g * 4 + c) * BS_STRIDE + j * 8] = w;
    }
  }

  // B-operand (x) loads: b = c*128 + wid*32 + sub*16 + row16 (pi-ordered k)
  short8 xfr[2][2][4];
#pragma unroll
  for (int c = 0; c < 2; ++c)
#pragma unroll
    for (int sub = 0; sub < 2; ++sub) {
      const int b = c * 128 + wid * 32 + sub * 16 + row16;
      const unsigned short* xptr = xb2 + ((size_t)m * B_ + b) * D_ + quad * 8;
#pragma unroll
      for (int ks = 0; ks < 4; ++ks) xfr[c][sub][ks] = *(const short8*)(xptr + ks * 32);
    }
  __syncthreads();  // Bs complete

  // ---- 2. GEMM + transpose-store (R12/R13-proven) ----
#pragma unroll
  for (int c = 0; c < 2; ++c) {  // chunk of 128 b
    floatx4 acc[2][4];
#pragma unroll
    for (int sub = 0; sub < 2; ++sub)
#pragma unroll
      for (int cf = 0; cf < 4; ++cf) acc[sub][cf] = (floatx4){0.f, 0.f, 0.f, 0.f};

#pragma unroll
    for (int cf = 0; cf < 4; ++cf) {
      short8 afr[4];
#pragma unroll
      for (int ks = 0; ks < 4; ++ks)
        afr[ks] = *(const short8*)&Bs[(cf * 16 + row16) * BS_STRIDE + ks * 32 + quad * 8];
#pragma unroll
      for (int ks = 0; ks < 4; ++ks)
#pragma unroll
        for (int sub = 0; sub < 2; ++sub)
          acc[sub][cf] = __builtin_amdgcn_mfma_f32_16x16x32_bf16(afr[ks], xfr[c][sub][ks], acc[sub][cf], 0, 0, 0);
    }

    if (c) __syncthreads();  // chunk-0 store phase must be done with Ct
#pragma unroll
    for (int sub = 0; sub < 2; ++sub)
#pragma unroll
      for (int cf = 0; cf < 4; ++cf) {
        ushort4 o4;
        o4.x = f2bf(acc[sub][cf][0]); o4.y = f2bf(acc[sub][cf][1]);
        o4.z = f2bf(acc[sub][cf][2]); o4.w = f2bf(acc[sub][cf][3]);
        *(ushort4*)&Ct[(wid * 32 + sub * 16 + row16) * 72 + cf * 16 + quad * 4] = o4;
      }
    __syncthreads();

    {  // store: 2 threads per b -> one 128B contiguous chunk at 8KB stride
      int q = tid >> 4, s = tid & 15;
      int row = q * 8 + (s >> 1);      // b_local 0..127
      int half = s & 1;
      int b = c * 128 + row;
      const unsigned short* src = &Ct[row * 72 + half * 32];
      unsigned short* dst = priors + (((size_t)n * B_ + b) * M_ + m) * T_ + half * 32;
      uint4 a0 = *(const uint4*)(src);
      uint4 a1 = *(const uint4*)(src + 8);
      uint4 a2 = *(const uint4*)(src + 16);
      uint4 a3 = *(const uint4*)(src + 24);
      *(uint4*)(dst) = a0;
      *(uint4*)(dst + 8) = a1;
      *(uint4*)(dst + 16) = a2;
      *(uint4*)(dst + 24) = a3;
    }
  }
}

// ---------------------------------------------------------------------------
// K2 (unchanged R12/R13): block = (n, g4); wave owns ONE b; priors[n][b][m][t]
// gives each wave ONE contiguous 8KB slab. No LDS staging, no barriers;
// rcp sigmoid/softmax; weighted sum reuses afr registers.
// ---------------------------------------------------------------------------
__global__ __launch_bounds__(256, 4) void k_route(const unsigned short* __restrict__ priors,
                                                  const unsigned short* __restrict__ lhn,
                                                  const float* __restrict__ thrT,
                                                  const float* __restrict__ gamma,
                                                  const float* __restrict__ beta,
                                                  float* __restrict__ out) {
  const int n = blockIdx.x, g4 = blockIdx.y;
  const int tid = threadIdx.x;
  const int wid = tid >> 6, lane = tid & 63;
  const int col = lane & 15, quad = lane >> 4;

  __shared__ float probL[4][64];

  const int b = g4 * 4 + wid;  // wave's batch element

  const unsigned short* base = priors + ((size_t)n * B_ + b) * (M_ * T_);  // 8KB contiguous
  short8 afr[4][2];  // A[m = mt*16+col][k(t) = ks*32+quad*8+j]
#pragma unroll
  for (int mt = 0; mt < 4; ++mt)
#pragma unroll
    for (int ks = 0; ks < 2; ++ks)
      afr[mt][ks] = *(const short8*)(base + (mt * 16 + col) * T_ + ks * 32 + quad * 8);

  float thv = thrT[n * 64 + lane];

  float dis[4][4];
#pragma unroll
  for (int mt = 0; mt < 4; ++mt)
#pragma unroll
    for (int r = 0; r < 4; ++r) dis[mt][r] = 0.f;

#pragma unroll
  for (int s4 = 0; s4 < 4; ++s4) {
    floatx4 acc[4][2];
#pragma unroll
    for (int mt = 0; mt < 4; ++mt)
#pragma unroll
      for (int lt = 0; lt < 2; ++lt) acc[mt][lt] = (floatx4){0.f, 0.f, 0.f, 0.f};

#pragma unroll
    for (int lt = 0; lt < 2; ++lt) {
#pragma unroll
      for (int ks = 0; ks < 2; ++ks) {
        short8 bfr = *(const short8*)(lhn + (s4 * 32 + lt * 16 + col) * T_ + ks * 32 + quad * 8);
#pragma unroll
        for (int mt = 0; mt < 4; ++mt)
          acc[mt][lt] = __builtin_amdgcn_mfma_f32_16x16x32_bf16(afr[mt][ks], bfr, acc[mt][lt], 0, 0, 0);
      }
    }

#pragma unroll
    for (int mt = 0; mt < 4; ++mt)
#pragma unroll
      for (int lt = 0; lt < 2; ++lt)
#pragma unroll
        for (int r = 0; r < 4; ++r)
          acc[mt][lt][r] = frcp(1.0f + __expf(-acc[mt][lt][r]));

    float mc[2];
#pragma unroll
    for (int lt = 0; lt < 2; ++lt) {
      float s = 0.f;
#pragma unroll
      for (int mt = 0; mt < 4; ++mt)
#pragma unroll
        for (int r = 0; r < 4; ++r) s += acc[mt][lt][r];
      s += __shfl_xor(s, 16);
      s += __shfl_xor(s, 32);
      mc[lt] = s * (1.0f / 64.0f);
    }

#pragma unroll
    for (int mt = 0; mt < 4; ++mt)
#pragma unroll
      for (int r = 0; r < 4; ++r) {
        float s = 0.f;
#pragma unroll
        for (int lt = 0; lt < 2; ++lt) {
          float df = acc[mt][lt][r] - mc[lt];
          s = fmaf(df, df, s);
        }
        dis[mt][r] += s;
      }
  }

#pragma unroll
  for (int off = 1; off <= 8; off <<= 1)
#pragma unroll
    for (int mt = 0; mt < 4; ++mt)
#pragma unroll
      for (int r = 0; r < 4; ++r) dis[mt][r] += __shfl_xor(dis[mt][r], off);

  float e[4][4];
  float mxw = 0.f;
#pragma unroll
  for (int mt = 0; mt < 4; ++mt)
#pragma unroll
    for (int r = 0; r < 4; ++r) {
      float th = __shfl(thv, mt * 16 + quad * 4 + r);
      float w = fmaxf(th * th - dis[mt][r] * (1.0f / 128.0f), 0.0f);
      e[mt][r] = w;
      mxw = fmaxf(mxw, w);
    }
  mxw = fmaxf(mxw, __shfl_xor(mxw, 16));
  mxw = fmaxf(mxw, __shfl_xor(mxw, 32));
  float ssum = 0.f;
#pragma unroll
  for (int mt = 0; mt < 4; ++mt)
#pragma unroll
    for (int r = 0; r < 4; ++r) {
      e[mt][r] = __expf(e[mt][r] - mxw);
      ssum += e[mt][r];
    }
  ssum += __shfl_xor(ssum, 16);
  ssum += __shfl_xor(ssum, 32);
  float inv = frcp(ssum);
  if (col == 0) {
#pragma unroll
    for (int mt = 0; mt < 4; ++mt)
#pragma unroll
      for (int r = 0; r < 4; ++r)
        probL[wid][mt * 16 + quad * 4 + r] = e[mt][r] * inv;
  }
  // same-wave LDS write->read: compiler inserts lgkmcnt wait (no barrier)

  float pr[4];
#pragma unroll
  for (int mt = 0; mt < 4; ++mt) pr[mt] = probL[wid][mt * 16 + col];

  float o[2][8];
#pragma unroll
  for (int ks = 0; ks < 2; ++ks)
#pragma unroll
    for (int j = 0; j < 8; ++j) o[ks][j] = 0.f;
#pragma unroll
  for (int mt = 0; mt < 4; ++mt)
#pragma unroll
    for (int ks = 0; ks < 2; ++ks)
#pragma unroll
      for (int j = 0; j < 8; ++j)
        o[ks][j] = fmaf(pr[mt], bf2f((unsigned short)afr[mt][ks][j]), o[ks][j]);
#pragma unroll
  for (int off = 1; off <= 8; off <<= 1)
#pragma unroll
    for (int ks = 0; ks < 2; ++ks)
#pragma unroll
      for (int j = 0; j < 8; ++j) o[ks][j] += __shfl_xor(o[ks][j], off);

  float mu = 0.f;
#pragma unroll
  for (int ks = 0; ks < 2; ++ks)
#pragma unroll
    for (int j = 0; j < 8; ++j) mu += o[ks][j];
  mu += __shfl_xor(mu, 16);
  mu += __shfl_xor(mu, 32);
  mu *= (1.0f / 64.0f);
  float var = 0.f;
#pragma unroll
  for (int ks = 0; ks < 2; ++ks)
#pragma unroll
    for (int j = 0; j < 8; ++j) {
      float d = o[ks][j] - mu;
      o[ks][j] = d;
      var = fmaf(d, d, var);
    }
  var += __shfl_xor(var, 16);
  var += __shfl_xor(var, 32);
  var *= (1.0f / 64.0f);
  float rstd = rsqrtf(var + 1e-5f);

  if (col == 0) {
    float* obase = out + ((size_t)b * N_ + n) * T_;
#pragma unroll
    for (int ks = 0; ks < 2; ++ks) {
      int tb = ks * 32 + quad * 8;
      float4 g0 = *(const float4*)(gamma + tb);
      float4 g1 = *(const float4*)(gamma + tb + 4);
      float4 b0 = *(const float4*)(beta + tb);
      float4 b1 = *(const float4*)(beta + tb + 4);
      float4 r0, r1;
      r0.x = o[ks][0] * rstd * g0.x + b0.x;
      r0.y = o[ks][1] * rstd * g0.y + b0.y;
      r0.z = o[ks][2] * rstd * g0.z + b0.z;
      r0.w = o[ks][3] * rstd * g0.w + b0.w;
      r1.x = o[ks][4] * rstd * g1.x + b1.x;
      r1.y = o[ks][5] * rstd * g1.y + b1.y;
      r1.z = o[ks][6] * rstd * g1.z + b1.z;
      r1.w = o[ks][7] * rstd * g1.w + b1.w;
      *(float4*)(obase + tb) = r0;
      *(float4*)(obase + tb + 4) = r1;
    }
  }
}

// ---------------------------------------------------------------------------
// Workspace layout (bytes):
//   priors [N][B][M][T]   bf16 : off 0,          67,108,864
//   xb2    [M][B][pi(D)]  bf16 : off 67,108,864,  4,194,304
//   LHn    [L][T]         bf16 : off 71,303,168,     16,384
//   thrT   [N][M]         fp32 : off 71,319,552,      8,192
// ---------------------------------------------------------------------------
extern "C" void kernel_launch(void* const* d_in, const int* in_sizes, int n_in,
                              void* d_out, int out_size, void* d_ws, size_t ws_size,
                              hipStream_t stream) {
  const float* x = (const float*)d_in[0];
  const float* rw = (const float*)d_in[1];
  const float* thr = (const float*)d_in[2];
  const float* leaves = (const float*)d_in[3];
  const float* gamma = (const float*)d_in[4];
  const float* beta = (const float*)d_in[5];
  float* out = (float*)d_out;

  char* ws = (char*)d_ws;
  unsigned short* priors = (unsigned short*)(ws);
  unsigned short* xb2 = (unsigned short*)(ws + 67108864);
  unsigned short* lhn = (unsigned short*)(ws + 71303168);
  float* thrT = (float*)(ws + 71319552);

  hipLaunchKernelGGL(k_prep, dim3(1026), dim3(256), 0, stream, x, leaves, xb2, lhn, thr, thrT);
  hipLaunchKernelGGL(k_wpriors, dim3(64, 32), dim3(256), 0, stream, xb2, rw, priors);
  hipLaunchKernelGGL(k_route, dim3(32, 64), dim3(256), 0, stream, priors, lhn, thrT, gamma, beta, out);
}

// Round 15
// 176.620 us; speedup vs baseline: 1.0193x; 1.0193x over previous
//
#include <hip/hip_runtime.h>
#include <hip/hip_bf16.h>
#include <math.h>

// Problem sizes (fixed by reference): B=256, M=64, N=32, D=128, T=64, L=128
#define B_ 256
#define M_ 64
#define N_ 32
#define D_ 128
#define T_ 64
#define L_ 128

typedef __attribute__((ext_vector_type(8))) short short8;   // 8 bf16 = 4 VGPRs (MFMA A/B frag)
typedef __attribute__((ext_vector_type(4))) float floatx4;  // MFMA C/D frag

__device__ __forceinline__ unsigned short f2bf(float f) {
  unsigned int u = __float_as_uint(f);
  unsigned int r = (u + 0x7fffu + ((u >> 16) & 1u)) >> 16;  // RNE
  return (unsigned short)r;
}
__device__ __forceinline__ float bf2f(unsigned short s) {
  return __uint_as_float(((unsigned int)s) << 16);
}
__device__ __forceinline__ float frcp(float x) { return __builtin_amdgcn_rcpf(x); }
// packed 2x f32 -> bf16x2 (low = a, high = b); lowers to HW packed cvt on gfx950
__device__ __forceinline__ unsigned pk2bf(float a, float b) {
  __hip_bfloat162 h = __float22bfloat162_rn(make_float2(a, b));
  unsigned u;
  __builtin_memcpy(&u, &h, 4);
  return u;
}

// ---------------------------------------------------------------------------
// K0: prep. blocks < 1024: x -> bf16 PI-PERMUTED xb2[m][b][pi(d)],
// pi(16i+j) = 8j+i (matches k_wpriors' entmax weight order -> GEMM dots
// unchanged). block 1024: leaves norm. 1025: thrT.
// ---------------------------------------------------------------------------
__global__ __launch_bounds__(256) void k_prep(const float* __restrict__ x,
                                              const float* __restrict__ leaves,
                                              unsigned short* __restrict__ xb2,
                                              unsigned short* __restrict__ lhn,
                                              const float* __restrict__ thr,
                                              float* __restrict__ thrT) {
  const int tid = threadIdx.x;
  const int bx = blockIdx.x;
  if (bx < 1024) {
    int idx = bx * 256 + tid;          // (m, b, j)
    int j = idx & 15, b = (idx >> 4) & 255, m = idx >> 12;
    const float* xs = x + ((size_t)b * M_ + m) * D_ + j;   // d = 16i + j
    float v[8];
#pragma unroll
    for (int i = 0; i < 8; ++i) v[i] = xs[i * 16];
    unsigned short* dst = xb2 + ((size_t)m * B_ + b) * D_ + j * 8;  // pi pos 8j+i
    uint4 w;
    w.x = pk2bf(v[0], v[1]);
    w.y = pk2bf(v[2], v[3]);
    w.z = pk2bf(v[4], v[5]);
    w.w = pk2bf(v[6], v[7]);
    *(uint4*)dst = w;
  } else if (bx == 1024) {
    if (tid < L_) {
      const float* r = leaves + tid * T_;
      float ss = 0.f;
      for (int i = 0; i < T_; ++i) ss = fmaf(r[i], r[i], ss);
      float inv = frcp(fmaxf(sqrtf(ss), 1e-12f));
      unsigned short* o = lhn + tid * T_;
      for (int i = 0; i < T_; ++i) o[i] = f2bf(r[i] * inv);
    }
  } else {  // thrT[n][m] = thr[m][n]
#pragma unroll
    for (int k = 0; k < 8; ++k) {
      int idx = k * 256 + tid;
      int nn = idx >> 6, mm = idx & 63;
      thrT[idx] = thr[mm * N_ + nn];
    }
  }
}

// ---------------------------------------------------------------------------
// K1 (R15): fused entmax + priors GEMM. vs R14: chunk-0 x-loads hoisted
// above entmax (fetch overlaps compute), 8 bisections (was 10), packed
// bf16 conversions everywhere (f2bf was ~5 VALU x ~96/thread).
// LDS: Bs 17.4KB + Ct 18KB = 35.4KB -> 4 blocks/CU.
// ---------------------------------------------------------------------------
#define BS_STRIDE 136
__global__ __launch_bounds__(256, 4) void k_wpriors(const unsigned short* __restrict__ xb2,
                                                    const float* __restrict__ rw,
                                                    unsigned short* __restrict__ priors) {
  const int m = blockIdx.x, n = blockIdx.y;
  const int tid = threadIdx.x;
  const int wid = tid >> 6, lane = tid & 63;
  const int row16 = lane & 15, quad = lane >> 4;

  __shared__ __align__(16) unsigned short Bs[64 * BS_STRIDE];  // W [t][pi_k] bf16
  __shared__ __align__(16) unsigned short Ct[128 * 72];        // [b_local][t]

  short8 xfr[2][2][4];
  // chunk-0 x loads up-front: in flight during entmax compute
#pragma unroll
  for (int sub = 0; sub < 2; ++sub) {
    const int b = wid * 32 + sub * 16 + row16;
    const unsigned short* xptr = xb2 + ((size_t)m * B_ + b) * D_ + quad * 8;
#pragma unroll
    for (int ks = 0; ks < 4; ++ks) xfr[0][sub][ks] = *(const short8*)(xptr + ks * 32);
  }

  // ---- 1. entmax (direct-global float4-along-T) ----
  {
    const int g = tid >> 4, j = tid & 15;
    const float* base = rw + (size_t)(m * N_ + n) * (D_ * T_) + g * 4;
    floatx4 xv[8];
#pragma unroll
    for (int i = 0; i < 8; ++i)
      xv[i] = *(const floatx4*)(base + (size_t)(i * 16 + j) * T_);

    floatx4 mx = xv[0];
#pragma unroll
    for (int i = 1; i < 8; ++i)
#pragma unroll
      for (int c = 0; c < 4; ++c) mx[c] = fmaxf(mx[c], xv[i][c]);
#pragma unroll
    for (int off = 1; off <= 8; off <<= 1)
#pragma unroll
      for (int c = 0; c < 4; ++c) mx[c] = fmaxf(mx[c], __shfl_xor(mx[c], off));
#pragma unroll
    for (int i = 0; i < 8; ++i)
#pragma unroll
      for (int c = 0; c < 4; ++c) xv[i][c] = (xv[i][c] - mx[c]) * 0.5f;

    floatx4 lo = (floatx4){-1.f, -1.f, -1.f, -1.f};
    floatx4 hi = (floatx4){0.f, 0.f, 0.f, 0.f};
    for (int it = 0; it < 8; ++it) {
      floatx4 tau, f = (floatx4){0.f, 0.f, 0.f, 0.f};
#pragma unroll
      for (int c = 0; c < 4; ++c) tau[c] = 0.5f * (lo[c] + hi[c]);
#pragma unroll
      for (int i = 0; i < 8; ++i)
#pragma unroll
        for (int c = 0; c < 4; ++c) {
          float u = fmaxf(xv[i][c] - tau[c], 0.0f);
          f[c] = fmaf(u, u, f[c]);
        }
#pragma unroll
      for (int off = 1; off <= 8; off <<= 1)
#pragma unroll
        for (int c = 0; c < 4; ++c) f[c] += __shfl_xor(f[c], off);
#pragma unroll
      for (int c = 0; c < 4; ++c) {
        bool ge = f[c] >= 1.0f;
        lo[c] = ge ? tau[c] : lo[c];
        hi[c] = ge ? hi[c] : tau[c];
      }
    }
    floatx4 tau0, cnt = (floatx4){0,0,0,0}, s1 = (floatx4){0,0,0,0}, s2 = (floatx4){0,0,0,0};
#pragma unroll
    for (int c = 0; c < 4; ++c) tau0[c] = 0.5f * (lo[c] + hi[c]);
#pragma unroll
    for (int i = 0; i < 8; ++i)
#pragma unroll
      for (int c = 0; c < 4; ++c) {
        bool in = xv[i][c] > tau0[c];
        float q = in ? xv[i][c] : 0.0f;
        cnt[c] += in ? 1.0f : 0.0f;
        s1[c] += q;
        s2[c] = fmaf(q, q, s2[c]);
      }
#pragma unroll
    for (int off = 1; off <= 8; off <<= 1)
#pragma unroll
      for (int c = 0; c < 4; ++c) {
        cnt[c] += __shfl_xor(cnt[c], off);
        s1[c] += __shfl_xor(s1[c], off);
        s2[c] += __shfl_xor(s2[c], off);
      }
    floatx4 tau;
#pragma unroll
    for (int c = 0; c < 4; ++c) {
      float rc = frcp(cnt[c]);
      float mean = s1[c] * rc;
      float ss = s2[c] - mean * s1[c];
      float delta = (1.0f - ss) * rc;
      tau[c] = mean - sqrtf(fmaxf(delta, 0.0f));
    }

    // weights -> Bs[t = 4g+c][pi = 8j + i]: one b128 write per t
#pragma unroll
    for (int c = 0; c < 4; ++c) {
      float u[8];
#pragma unroll
      for (int i = 0; i < 8; ++i) {
        float v = fmaxf(xv[i][c] - tau[c], 0.0f);
        u[i] = v * v;
      }
      uint4 w;
      w.x = pk2bf(u[0], u[1]);
      w.y = pk2bf(u[2], u[3]);
      w.z = pk2bf(u[4], u[5]);
      w.w = pk2bf(u[6], u[7]);
      *(uint4*)&Bs[(g * 4 + c) * BS_STRIDE + j * 8] = w;
    }
  }

  // chunk-1 x loads (overlap with GEMM chunk 0)
#pragma unroll
  for (int sub = 0; sub < 2; ++sub) {
    const int b = 128 + wid * 32 + sub * 16 + row16;
    const unsigned short* xptr = xb2 + ((size_t)m * B_ + b) * D_ + quad * 8;
#pragma unroll
    for (int ks = 0; ks < 4; ++ks) xfr[1][sub][ks] = *(const short8*)(xptr + ks * 32);
  }
  __syncthreads();  // Bs complete

  // ---- 2. GEMM + transpose-store ----
#pragma unroll
  for (int c = 0; c < 2; ++c) {  // chunk of 128 b
    floatx4 acc[2][4];
#pragma unroll
    for (int sub = 0; sub < 2; ++sub)
#pragma unroll
      for (int cf = 0; cf < 4; ++cf) acc[sub][cf] = (floatx4){0.f, 0.f, 0.f, 0.f};

#pragma unroll
    for (int cf = 0; cf < 4; ++cf) {
      short8 afr[4];
#pragma unroll
      for (int ks = 0; ks < 4; ++ks)
        afr[ks] = *(const short8*)&Bs[(cf * 16 + row16) * BS_STRIDE + ks * 32 + quad * 8];
#pragma unroll
      for (int ks = 0; ks < 4; ++ks)
#pragma unroll
        for (int sub = 0; sub < 2; ++sub)
          acc[sub][cf] = __builtin_amdgcn_mfma_f32_16x16x32_bf16(afr[ks], xfr[c][sub][ks], acc[sub][cf], 0, 0, 0);
    }

    if (c) __syncthreads();  // chunk-0 store phase must be done with Ct
#pragma unroll
    for (int sub = 0; sub < 2; ++sub)
#pragma unroll
      for (int cf = 0; cf < 4; ++cf) {
        uint2 o2;
        o2.x = pk2bf(acc[sub][cf][0], acc[sub][cf][1]);
        o2.y = pk2bf(acc[sub][cf][2], acc[sub][cf][3]);
        *(uint2*)&Ct[(wid * 32 + sub * 16 + row16) * 72 + cf * 16 + quad * 4] = o2;
      }
    __syncthreads();

    {  // store: 2 threads per b -> one 128B contiguous chunk at 8KB stride
      int q = tid >> 4, s = tid & 15;
      int row = q * 8 + (s >> 1);      // b_local 0..127
      int half = s & 1;
      int b = c * 128 + row;
      const unsigned short* src = &Ct[row * 72 + half * 32];
      unsigned short* dst = priors + (((size_t)n * B_ + b) * M_ + m) * T_ + half * 32;
      uint4 a0 = *(const uint4*)(src);
      uint4 a1 = *(const uint4*)(src + 8);
      uint4 a2 = *(const uint4*)(src + 16);
      uint4 a3 = *(const uint4*)(src + 24);
      *(uint4*)(dst) = a0;
      *(uint4*)(dst + 8) = a1;
      *(uint4*)(dst + 16) = a2;
      *(uint4*)(dst + 24) = a3;
    }
  }
}

// ---------------------------------------------------------------------------
// K2 (unchanged R12/R13): block = (n, g4); wave owns ONE b; priors[n][b][m][t]
// gives each wave ONE contiguous 8KB slab. No LDS staging, no barriers;
// rcp sigmoid/softmax; weighted sum reuses afr registers.
// ---------------------------------------------------------------------------
__global__ __launch_bounds__(256, 4) void k_route(const unsigned short* __restrict__ priors,
                                                  const unsigned short* __restrict__ lhn,
                                                  const float* __restrict__ thrT,
                                                  const float* __restrict__ gamma,
                                                  const float* __restrict__ beta,
                                                  float* __restrict__ out) {
  const int n = blockIdx.x, g4 = blockIdx.y;
  const int tid = threadIdx.x;
  const int wid = tid >> 6, lane = tid & 63;
  const int col = lane & 15, quad = lane >> 4;

  __shared__ float probL[4][64];

  const int b = g4 * 4 + wid;  // wave's batch element

  const unsigned short* base = priors + ((size_t)n * B_ + b) * (M_ * T_);  // 8KB contiguous
  short8 afr[4][2];  // A[m = mt*16+col][k(t) = ks*32+quad*8+j]
#pragma unroll
  for (int mt = 0; mt < 4; ++mt)
#pragma unroll
    for (int ks = 0; ks < 2; ++ks)
      afr[mt][ks] = *(const short8*)(base + (mt * 16 + col) * T_ + ks * 32 + quad * 8);

  float thv = thrT[n * 64 + lane];

  float dis[4][4];
#pragma unroll
  for (int mt = 0; mt < 4; ++mt)
#pragma unroll
    for (int r = 0; r < 4; ++r) dis[mt][r] = 0.f;

#pragma unroll
  for (int s4 = 0; s4 < 4; ++s4) {
    floatx4 acc[4][2];
#pragma unroll
    for (int mt = 0; mt < 4; ++mt)
#pragma unroll
      for (int lt = 0; lt < 2; ++lt) acc[mt][lt] = (floatx4){0.f, 0.f, 0.f, 0.f};

#pragma unroll
    for (int lt = 0; lt < 2; ++lt) {
#pragma unroll
      for (int ks = 0; ks < 2; ++ks) {
        short8 bfr = *(const short8*)(lhn + (s4 * 32 + lt * 16 + col) * T_ + ks * 32 + quad * 8);
#pragma unroll
        for (int mt = 0; mt < 4; ++mt)
          acc[mt][lt] = __builtin_amdgcn_mfma_f32_16x16x32_bf16(afr[mt][ks], bfr, acc[mt][lt], 0, 0, 0);
      }
    }

#pragma unroll
    for (int mt = 0; mt < 4; ++mt)
#pragma unroll
      for (int lt = 0; lt < 2; ++lt)
#pragma unroll
        for (int r = 0; r < 4; ++r)
          acc[mt][lt][r] = frcp(1.0f + __expf(-acc[mt][lt][r]));

    float mc[2];
#pragma unroll
    for (int lt = 0; lt < 2; ++lt) {
      float s = 0.f;
#pragma unroll
      for (int mt = 0; mt < 4; ++mt)
#pragma unroll
        for (int r = 0; r < 4; ++r) s += acc[mt][lt][r];
      s += __shfl_xor(s, 16);
      s += __shfl_xor(s, 32);
      mc[lt] = s * (1.0f / 64.0f);
    }

#pragma unroll
    for (int mt = 0; mt < 4; ++mt)
#pragma unroll
      for (int r = 0; r < 4; ++r) {
        float s = 0.f;
#pragma unroll
        for (int lt = 0; lt < 2; ++lt) {
          float df = acc[mt][lt][r] - mc[lt];
          s = fmaf(df, df, s);
        }
        dis[mt][r] += s;
      }
  }

#pragma unroll
  for (int off = 1; off <= 8; off <<= 1)
#pragma unroll
    for (int mt = 0; mt < 4; ++mt)
#pragma unroll
      for (int r = 0; r < 4; ++r) dis[mt][r] += __shfl_xor(dis[mt][r], off);

  float e[4][4];
  float mxw = 0.f;
#pragma unroll
  for (int mt = 0; mt < 4; ++mt)
#pragma unroll
    for (int r = 0; r < 4; ++r) {
      float th = __shfl(thv, mt * 16 + quad * 4 + r);
      float w = fmaxf(th * th - dis[mt][r] * (1.0f / 128.0f), 0.0f);
      e[mt][r] = w;
      mxw = fmaxf(mxw, w);
    }
  mxw = fmaxf(mxw, __shfl_xor(mxw, 16));
  mxw = fmaxf(mxw, __shfl_xor(mxw, 32));
  float ssum = 0.f;
#pragma unroll
  for (int mt = 0; mt < 4; ++mt)
#pragma unroll
    for (int r = 0; r < 4; ++r) {
      e[mt][r] = __expf(e[mt][r] - mxw);
      ssum += e[mt][r];
    }
  ssum += __shfl_xor(ssum, 16);
  ssum += __shfl_xor(ssum, 32);
  float inv = frcp(ssum);
  if (col == 0) {
#pragma unroll
    for (int mt = 0; mt < 4; ++mt)
#pragma unroll
      for (int r = 0; r < 4; ++r)
        probL[wid][mt * 16 + quad * 4 + r] = e[mt][r] * inv;
  }
  // same-wave LDS write->read: compiler inserts lgkmcnt wait (no barrier)

  float pr[4];
#pragma unroll
  for (int mt = 0; mt < 4; ++mt) pr[mt] = probL[wid][mt * 16 + col];

  float o[2][8];
#pragma unroll
  for (int ks = 0; ks < 2; ++ks)
#pragma unroll
    for (int j = 0; j < 8; ++j) o[ks][j] = 0.f;
#pragma unroll
  for (int mt = 0; mt < 4; ++mt)
#pragma unroll
    for (int ks = 0; ks < 2; ++ks)
#pragma unroll
      for (int j = 0; j < 8; ++j)
        o[ks][j] = fmaf(pr[mt], bf2f((unsigned short)afr[mt][ks][j]), o[ks][j]);
#pragma unroll
  for (int off = 1; off <= 8; off <<= 1)
#pragma unroll
    for (int ks = 0; ks < 2; ++ks)
#pragma unroll
      for (int j = 0; j < 8; ++j) o[ks][j] += __shfl_xor(o[ks][j], off);

  float mu = 0.f;
#pragma unroll
  for (int ks = 0; ks < 2; ++ks)
#pragma unroll
    for (int j = 0; j < 8; ++j) mu += o[ks][j];
  mu += __shfl_xor(mu, 16);
  mu += __shfl_xor(mu, 32);
  mu *= (1.0f / 64.0f);
  float var = 0.f;
#pragma unroll
  for (int ks = 0; ks < 2; ++ks)
#pragma unroll
    for (int j = 0; j < 8; ++j) {
      float d = o[ks][j] - mu;
      o[ks][j] = d;
      var = fmaf(d, d, var);
    }
  var += __shfl_xor(var, 16);
  var += __shfl_xor(var, 32);
  var *= (1.0f / 64.0f);
  float rstd = rsqrtf(var + 1e-5f);

  if (col == 0) {
    float* obase = out + ((size_t)b * N_ + n) * T_;
#pragma unroll
    for (int ks = 0; ks < 2; ++ks) {
      int tb = ks * 32 + quad * 8;
      float4 g0 = *(const float4*)(gamma + tb);
      float4 g1 = *(const float4*)(gamma + tb + 4);
      float4 b0 = *(const float4*)(beta + tb);
      float4 b1 = *(const float4*)(beta + tb + 4);
      float4 r0, r1;
      r0.x = o[ks][0] * rstd * g0.x + b0.x;
      r0.y = o[ks][1] * rstd * g0.y + b0.y;
      r0.z = o[ks][2] * rstd * g0.z + b0.z;
      r0.w = o[ks][3] * rstd * g0.w + b0.w;
      r1.x = o[ks][4] * rstd * g1.x + b1.x;
      r1.y = o[ks][5] * rstd * g1.y + b1.y;
      r1.z = o[ks][6] * rstd * g1.z + b1.z;
      r1.w = o[ks][7] * rstd * g1.w + b1.w;
      *(float4*)(obase + tb) = r0;
      *(float4*)(obase + tb + 4) = r1;
    }
  }
}

// ---------------------------------------------------------------------------
// Workspace layout (bytes):
//   priors [N][B][M][T]   bf16 : off 0,          67,108,864
//   xb2    [M][B][pi(D)]  bf16 : off 67,108,864,  4,194,304
//   LHn    [L][T]         bf16 : off 71,303,168,     16,384
//   thrT   [N][M]         fp32 : off 71,319,552,      8,192
// ---------------------------------------------------------------------------
extern "C" void kernel_launch(void* const* d_in, const int* in_sizes, int n_in,
                              void* d_out, int out_size, void* d_ws, size_t ws_size,
                              hipStream_t stream) {
  const float* x = (const float*)d_in[0];
  const float* rw = (const float*)d_in[1];
  const float* thr = (const float*)d_in[2];
  const float* leaves = (const float*)d_in[3];
  const float* gamma = (const float*)d_in[4];
  const float* beta = (const float*)d_in[5];
  float* out = (float*)d_out;

  char* ws = (char*)d_ws;
  unsigned short* priors = (unsigned short*)(ws);
  unsigned short* xb2 = (unsigned short*)(ws + 67108864);
  unsigned short* lhn = (unsigned short*)(ws + 71303168);
  float* thrT = (float*)(ws + 71319552);

  hipLaunchKernelGGL(k_prep, dim3(1026), dim3(256), 0, stream, x, leaves, xb2, lhn, thr, thrT);
  hipLaunchKernelGGL(k_wpriors, dim3(64, 32), dim3(256), 0, stream, xb2, rw, priors);
  hipLaunchKernelGGL(k_route, dim3(32, 64), dim3(256), 0, stream, priors, lhn, thrT, gamma, beta, out);
}